// Round 6
// baseline (552.624 us; speedup 1.0000x reference)
//
#include <hip/hip_runtime.h>

// Problem constants (MeshConv: B=8, M=40000, FIN=64, K=6, FOUT=64, NNZ=320000)
#define Mn    40000
#define Bn    8
#define FINn  64
#define Kn    6
#define FOUTn 64
#define NNZn  320000
#define Cn    512   // FIN*B values per level row; c = b*64 + f
#define NB    ((Mn + 255) / 256)   // scan blocks = 157
#define MT    (Mn / 64)            // 625 m-tiles for the GEMM
#define NCB   8                    // SpMM column blocks (64 halves = 128B each)
#define MCH   (Mn / 32)            // SpMM m-chunks (32 rows per block) = 1250

// Level layout (fp16): xh[lev][m][c] -- one row = 1KB contiguous.
// SpMM gathers a 128B c-slice per edge (one cache line); GEMM reads
// 64-row x 128B tiles per (b, m-tile).

typedef _Float16 half8 __attribute__((ext_vector_type(8)));  // MFMA A/B frag
typedef __attribute__((ext_vector_type(4))) float floatx4;   // MFMA accumulator

__device__ __forceinline__ ushort f2h(float f) {
    _Float16 h = (_Float16)f;
    return *(ushort*)&h;
}

// async global->LDS, 16B per lane; dst must be wave-uniform base (HW adds lane*16)
__device__ __forceinline__ void gl_lds16(const ushort* g, ushort* l) {
    __builtin_amdgcn_global_load_lds(
        (const __attribute__((address_space(1))) unsigned int*)g,
        (__attribute__((address_space(3))) unsigned int*)l, 16, 0, 0);
}

// ---------------- CSR build ----------------

__global__ __launch_bounds__(256) void k_hist(const int* __restrict__ rows,
                                              int* __restrict__ cnt) {
    int e = blockIdx.x * 256 + threadIdx.x;
    if (e < NNZn) atomicAdd(&cnt[rows[e]], 1);
}

__global__ __launch_bounds__(256) void k_scan_part(const int* __restrict__ cnt,
                                                   int* __restrict__ rowptr,
                                                   int* __restrict__ bsum) {
    __shared__ int part[256];
    int tid = threadIdx.x;
    int r = blockIdx.x * 256 + tid;
    int v = (r < Mn) ? cnt[r] : 0;
    part[tid] = v;
    __syncthreads();
    for (int off = 1; off < 256; off <<= 1) {
        int t = (tid >= off) ? part[tid - off] : 0;
        __syncthreads();
        part[tid] += t;
        __syncthreads();
    }
    if (r < Mn) rowptr[r] = part[tid] - v;
    if (tid == 255) bsum[blockIdx.x] = part[255];
}

__global__ __launch_bounds__(256) void k_scan_bsums(const int* __restrict__ bsum,
                                                    int* __restrict__ boff,
                                                    int* __restrict__ rowptr) {
    __shared__ int part[256];
    int tid = threadIdx.x;
    int v = (tid < NB) ? bsum[tid] : 0;
    part[tid] = v;
    __syncthreads();
    for (int off = 1; off < 256; off <<= 1) {
        int t = (tid >= off) ? part[tid - off] : 0;
        __syncthreads();
        part[tid] += t;
        __syncthreads();
    }
    if (tid < NB) boff[tid] = part[tid] - v;
    if (tid == 255) rowptr[Mn] = part[255];
}

__global__ __launch_bounds__(256) void k_scan_add(int* __restrict__ rowptr,
                                                  const int* __restrict__ boff,
                                                  int* __restrict__ wcur) {
    int r = blockIdx.x * 256 + threadIdx.x;
    if (r < Mn) {
        int v = rowptr[r] + boff[blockIdx.x];
        rowptr[r] = v;
        wcur[r] = v;
    }
}

__global__ __launch_bounds__(256) void k_scatter(const int* __restrict__ rows,
                                                 const int* __restrict__ cols,
                                                 const float* __restrict__ vals,
                                                 int* __restrict__ wcur,
                                                 int2* __restrict__ csr) {
    int e = blockIdx.x * 256 + threadIdx.x;
    if (e < NNZn) {
        int p = atomicAdd(&wcur[rows[e]], 1);
        int2 cv; cv.x = cols[e]; cv.y = __float_as_int(vals[e]);
        csr[p] = cv;
    }
}

// ---------------- x -> x0 (fp16): transpose to [m][b*64+f] ----------------

__global__ __launch_bounds__(256) void k_transpose_h(const float* __restrict__ x,
                                                     ushort* __restrict__ x0h) {
    int m0 = blockIdx.x * 4;
    int t  = threadIdx.x;
#pragma unroll
    for (int k = 0; k < 2; ++k) {
        int i   = t + k * 256;       // 0..511
        int ml  = i >> 7;            // 0..3
        int rem = i & 127;
        int b   = rem >> 4;
        int fq  = (rem & 15) * 4;
        float4 a = *(const float4*)(x + ((size_t)b * Mn + m0 + ml) * 64 + fq);
        union { uint2 u; ushort h[4]; } s;
        s.h[0] = f2h(a.x); s.h[1] = f2h(a.y); s.h[2] = f2h(a.z); s.h[3] = f2h(a.w);
        *(uint2*)(x0h + (size_t)(m0 + ml) * Cn + b * 64 + fq) = s.u;
    }
}

// ---------------- SpMM, c-blocked (all-fp16 state) + Chebyshev ----------------
// Grid ordered c-block-major: blocks working concurrently share a 1-2 c-block
// window (5-10MB) so gathers mostly hit XCD-local L2 instead of crossing the
// fabric to LLC (random graph: locality only comes from working-set shrink).
// Wave = 8 rows x 8 lanes (16B each -> 128B slice = 1 line per edge-gather).

__device__ __forceinline__ void fmah8(float* a, uint4 g, float w) {
    union { uint4 u; _Float16 h[8]; } c; c.u = g;
#pragma unroll
    for (int i = 0; i < 8; ++i) a[i] += w * (float)c.h[i];
}

__global__ __launch_bounds__(256) void k_spmm_h(const ushort* __restrict__ xc,
                                                const ushort* __restrict__ xp,
                                                ushort* __restrict__ xn,
                                                const int* __restrict__ rowptr,
                                                const int2* __restrict__ csr,
                                                int first) {
    int t    = threadIdx.x;
    int lane = t & 63;
    int wv   = t >> 6;
    int cblk = blockIdx.x / MCH;                 // c-block-major ordering
    int mch  = blockIdx.x % MCH;
    int r    = mch * 32 + wv * 8 + (lane >> 3);  // this lane's row
    int coff = cblk * 8 + (lane & 7);            // uint4 offset within 1KB row

    const uint4* xc4 = (const uint4*)xc;
    uint4 v = xc4[(size_t)r * 64 + coff];
    uint4 p;
    if (!first) p = ((const uint4*)xp)[(size_t)r * 64 + coff];   // early issue
    int rp0 = rowptr[r], rp1 = rowptr[r + 1];

    float a[8];
    { union { uint4 u; _Float16 h[8]; } c; c.u = v;
#pragma unroll
      for (int i = 0; i < 8; ++i) a[i] = -(float)c.h[i]; }

    int it = 0;
    while (__any(rp0 + it < rp1)) {
#pragma unroll
        for (int u = 0; u < 4; ++u) {
            int e  = rp0 + it + u;
            int ec = (e < rp1) ? e : (rp1 - 1);
            ec = (ec < 0) ? 0 : ec;
            int2 cv = csr[ec];
            float w = (e < rp1) ? __int_as_float(cv.y) : 0.f;
            uint4 g = xc4[(size_t)cv.x * 64 + coff];
            fmah8(a, g, w);
        }
        it += 4;
    }

    if (!first) {
        union { uint4 u; _Float16 h[8]; } c; c.u = p;
#pragma unroll
        for (int i = 0; i < 8; ++i) a[i] = 2.f * a[i] - (float)c.h[i];
    }
    union { uint4 u; _Float16 h[8]; } s;
#pragma unroll
    for (int i = 0; i < 8; ++i) s.h[i] = (_Float16)a[i];
    ((uint4*)xn)[(size_t)r * 64 + coff] = s.u;
}

// ---------------- W -> MFMA B-fragment pre-swizzle (fp16) ----------------

__global__ __launch_bounds__(256) void k_wfrag(const float* __restrict__ W,
                                               ushort* __restrict__ wfrag) {
    int idx = blockIdx.x * 256 + threadIdx.x;   // 12*4*64*8 = 24576
    if (idx >= 12 * 4 * 64 * 8) return;
    int j    = idx & 7;
    int lane = (idx >> 3) & 63;
    int n    = (idx >> 9) & 3;
    int kk   = idx >> 11;
    int k    = (lane >> 4) * 8 + j;
    int lev  = kk >> 1;
    int f    = (kk & 1) * 32 + k;
    int fo   = n * 16 + (lane & 15);
    wfrag[idx] = f2h(W[(f * Kn + lev) * FOUTn + fo]);
}

// ---------------- MFMA projection GEMM (fp16 inputs, fp32 acc) ----------------
// out[b, m, fo] = sum over 6 levels, f of X[lev][m][b*64+f] * W[(f*6+lev)*64+fo]
// All 6 levels' A-tiles (8KB each) are prefetched via async global_load_lds
// into 6 separate LDS regions at kernel entry (payload in LDS -> regalloc
// can't sink it, unlike R4/R5's register prefetch), then ONE __syncthreads
// (drains vmcnt) and the full 12-step MFMA ladder. XOR swizzle is applied on
// the GLOBAL source granule (linear LDS dest requirement) and re-applied on
// the ds_read side -- R2 measured this read pattern at 0 bank conflicts.

__global__ __launch_bounds__(256, 2) void k_gemm_mfma(const ushort* __restrict__ xh,
                                                      const ushort* __restrict__ wfrag,
                                                      float* __restrict__ out) {
    __shared__ __align__(16) ushort As[6][64 * 64];   // 48KB: 6 x (64 rows x 128B)
    int t     = threadIdx.x;
    int wv    = t >> 6;
    int lane  = t & 63;
    int q     = lane >> 4, r = lane & 15;
    int mtile = blockIdx.x % MT;
    int b     = blockIdx.x / MT;
    int m0    = mtile * 64;

    const size_t lstrideH = (size_t)Mn * Cn;   // level stride in halves

    // staging: chunk c in {0,1}; thread covers row = c*32 + wv*8 + (lane>>3),
    // LDS dest linear (wave base + lane*16); global source granule pre-XOR'd.
    int srow = wv * 8 + (lane >> 3);
    int gsw  = (lane & 7) ^ (srow & 7);        // (srow+32)&7 == srow&7
    const ushort* gs0 = xh + (size_t)(m0 + srow) * Cn + b * 64 + gsw * 8;
    const ushort* gs1 = gs0 + (size_t)32 * Cn;
#pragma unroll
    for (int lev = 0; lev < 6; ++lev) {
        gl_lds16(gs0 + lev * lstrideH, &As[lev][wv * 512]);
        gl_lds16(gs1 + lev * lstrideH, &As[lev][2048 + wv * 512]);
    }
    __syncthreads();   // drains vmcnt; all 6 tiles visible. One stall per block.

    floatx4 acc[4];
    acc[0] = (floatx4)0.f; acc[1] = (floatx4)0.f;
    acc[2] = (floatx4)0.f; acc[3] = (floatx4)0.f;

    int row = wv * 16 + r;
#define MC_HALF(lev, half)                                                            \
    do {                                                                              \
        int gran = ((half) * 4 + q) ^ (row & 7);                                      \
        half8 af = *(const half8*)&As[lev][row * 64 + (gran << 3)];                   \
        const ushort* wf = wfrag + ((size_t)(((lev) * 2 + (half)) * 4) * 64 + lane) * 8; \
        acc[0] = __builtin_amdgcn_mfma_f32_16x16x32_f16(af, *(const half8*)(wf),        acc[0], 0, 0, 0); \
        acc[1] = __builtin_amdgcn_mfma_f32_16x16x32_f16(af, *(const half8*)(wf + 512),  acc[1], 0, 0, 0); \
        acc[2] = __builtin_amdgcn_mfma_f32_16x16x32_f16(af, *(const half8*)(wf + 1024), acc[2], 0, 0, 0); \
        acc[3] = __builtin_amdgcn_mfma_f32_16x16x32_f16(af, *(const half8*)(wf + 1536), acc[3], 0, 0, 0); \
    } while (0)

    MC_HALF(0, 0); MC_HALF(0, 1);
    MC_HALF(1, 0); MC_HALF(1, 1);
    MC_HALF(2, 0); MC_HALF(2, 1);
    MC_HALF(3, 0); MC_HALF(3, 1);
    MC_HALF(4, 0); MC_HALF(4, 1);
    MC_HALF(5, 0); MC_HALF(5, 1);
#undef MC_HALF

    // C/D layout: col = lane&15, row = (lane>>4)*4 + reg
    size_t obase = ((size_t)b * Mn + m0 + wv * 16) * FOUTn;
#pragma unroll
    for (int n = 0; n < 4; ++n) {
#pragma unroll
        for (int reg = 0; reg < 4; ++reg) {
            int orow = q * 4 + reg;
            out[obase + (size_t)orow * FOUTn + n * 16 + r] = acc[n][reg];
        }
    }
}

// ---------------- fallback fp32 kernels (ws too small; not expected) ----------------

__global__ __launch_bounds__(512) void k_transpose_f(const float* __restrict__ x,
                                                     float* __restrict__ x0) {
    int m = blockIdx.x, t = threadIdx.x;
    int b = t >> 6, f = t & 63;
    x0[(size_t)m * Cn + t] = x[((size_t)b * Mn + m) * 64 + f];
}

__global__ __launch_bounds__(256) void k_spmm_f32(const float4* __restrict__ xc,
                                                  const float4* __restrict__ xp,
                                                  float4* __restrict__ xn,
                                                  const int* __restrict__ rowptr,
                                                  const int2* __restrict__ csr,
                                                  int first) {
    int t = threadIdx.x;
    int lane = t & 63;
    int m = blockIdx.x * 4 + (t >> 6);
    size_t rb = (size_t)m * 128;
    float4 v0 = xc[rb + lane];
    float4 v1 = xc[rb + 64 + lane];
    float4 a0 = make_float4(-v0.x, -v0.y, -v0.z, -v0.w);
    float4 a1 = make_float4(-v1.x, -v1.y, -v1.z, -v1.w);
    int e = rowptr[m], end = rowptr[m + 1];
    for (; e < end; ++e) {
        int2 cv = csr[e];
        float w = __int_as_float(cv.y);
        const float4* r = xc + (size_t)cv.x * 128;
        float4 g0 = r[lane], g1 = r[64 + lane];
        a0.x += w * g0.x; a0.y += w * g0.y; a0.z += w * g0.z; a0.w += w * g0.w;
        a1.x += w * g1.x; a1.y += w * g1.y; a1.z += w * g1.z; a1.w += w * g1.w;
    }
    if (!first) {
        float4 p0 = xp[rb + lane];
        float4 p1 = xp[rb + 64 + lane];
        a0.x = 2.f * a0.x - p0.x; a0.y = 2.f * a0.y - p0.y;
        a0.z = 2.f * a0.z - p0.z; a0.w = 2.f * a0.w - p0.w;
        a1.x = 2.f * a1.x - p1.x; a1.y = 2.f * a1.y - p1.y;
        a1.z = 2.f * a1.z - p1.z; a1.w = 2.f * a1.w - p1.w;
    }
    xn[rb + lane] = a0;
    xn[rb + 64 + lane] = a1;
}

__global__ __launch_bounds__(256) void k_gemm2(const float* __restrict__ xa,
                                               const float* __restrict__ xb,
                                               const float* __restrict__ W,
                                               float* __restrict__ out,
                                               int ka, int kb, int accum) {
    __shared__ __align__(16) float Wa[64 * 64];
    __shared__ __align__(16) float Wb[64 * 64];
    __shared__ __align__(16) float xsa[4 * Cn];
    __shared__ __align__(16) float xsb[4 * Cn];
    int t = threadIdx.x;
    size_t m0 = (size_t)blockIdx.x * 4;
    for (int i = t; i < 4096; i += 256) {
        int f = i >> 6, fo = i & 63;
        Wa[i] = W[(f * Kn + ka) * FOUTn + fo];
        Wb[i] = W[(f * Kn + kb) * FOUTn + fo];
    }
    for (int i = t; i < 4 * Cn; i += 256) {
        xsa[i] = xa[m0 * Cn + i];
        xsb[i] = xb[m0 * Cn + i];
    }
    __syncthreads();
    int fo  = (t & 15) * 4;
    int idx = t >> 4;
    int m   = idx & 3;
    int bq  = idx >> 2;
    float4 acc0 = make_float4(0.f, 0.f, 0.f, 0.f);
    float4 acc1 = make_float4(0.f, 0.f, 0.f, 0.f);
    for (int f = 0; f < 64; ++f) {
        float4 wa = *(const float4*)&Wa[f * 64 + fo];
        float a0 = xsa[m * Cn + bq * 64 + f];
        float a1 = xsa[m * Cn + (bq + 4) * 64 + f];
        acc0.x += a0 * wa.x; acc0.y += a0 * wa.y; acc0.z += a0 * wa.z; acc0.w += a0 * wa.w;
        acc1.x += a1 * wa.x; acc1.y += a1 * wa.y; acc1.z += a1 * wa.z; acc1.w += a1 * wa.w;
        float4 wb = *(const float4*)&Wb[f * 64 + fo];
        float b0 = xsb[m * Cn + bq * 64 + f];
        float b1 = xsb[m * Cn + (bq + 4) * 64 + f];
        acc0.x += b0 * wb.x; acc0.y += b0 * wb.y; acc0.z += b0 * wb.z; acc0.w += b0 * wb.w;
        acc1.x += b1 * wb.x; acc1.y += b1 * wb.y; acc1.z += b1 * wb.z; acc1.w += b1 * wb.w;
    }
    size_t o0 = (((size_t)bq * Mn) + (m0 + m)) * FOUTn + fo;
    size_t o1 = (((size_t)(bq + 4) * Mn) + (m0 + m)) * FOUTn + fo;
    float4* out4_0 = (float4*)&out[o0];
    float4* out4_1 = (float4*)&out[o1];
    if (accum) {
        float4 c0 = *out4_0, c1 = *out4_1;
        acc0.x += c0.x; acc0.y += c0.y; acc0.z += c0.z; acc0.w += c0.w;
        acc1.x += c1.x; acc1.y += c1.y; acc1.z += c1.z; acc1.w += c1.w;
    }
    *out4_0 = acc0;
    *out4_1 = acc1;
}

// ---------------- launch ----------------

extern "C" void kernel_launch(void* const* d_in, const int* in_sizes, int n_in,
                              void* d_out, int out_size, void* d_ws, size_t ws_size,
                              hipStream_t stream) {
    const float* x         = (const float*)d_in[0];
    const float* edge_vals = (const float*)d_in[1];
    const float* W         = (const float*)d_in[2];
    const int*   edge_rows = (const int*)d_in[3];
    const int*   edge_cols = (const int*)d_in[4];
    float* out = (float*)d_out;

    char* ws = (char*)d_ws;
    const size_t bufB = (size_t)Mn * Cn * sizeof(float);   // 81.92 MB fp32 level
    const size_t bufH = (size_t)Mn * Cn * sizeof(ushort);  // 40.96 MB fp16 level
    const size_t wfB  = 12 * 4 * 64 * 8 * sizeof(ushort);  // 48 KB
    const size_t csrB = (size_t)(Mn + 4 + Mn) * 4 + (size_t)NNZn * 8;  // ~2.9 MB

    const int spmm_grid = NCB * MCH;   // 10000, c-block-major
    const int gemm_grid = MT * 8;      // 5000

    // primary plan: 6 fp16 level slots (248.69 MB total), layout [lev][m][c]
    if (ws_size >= 6 * bufH + wfB + csrB) {
        ushort* xh  = (ushort*)ws;                       // slot l at xh + l*Mn*Cn
        ushort* wfr = (ushort*)(ws + 6 * bufH);
        int*    rowptr = (int*)(ws + 6 * bufH + wfB);
        int*    fill   = rowptr + (Mn + 4);              // doubles as wcur
        int2*   csr    = (int2*)(fill + Mn);
        int*    bsum   = (int*)csr;                      // scan scratch in csr buf
        int*    boff   = bsum + 256;
        ushort* slot[6];
        for (int l = 0; l < 6; ++l) slot[l] = xh + (size_t)l * Mn * Cn;

        // CSR build (every call; ws re-poisoned by harness)
        hipMemsetAsync(fill, 0, Mn * sizeof(int), stream);
        k_hist<<<(NNZn + 255) / 256, 256, 0, stream>>>(edge_rows, fill);
        k_scan_part<<<NB, 256, 0, stream>>>(fill, rowptr, bsum);
        k_scan_bsums<<<1, 256, 0, stream>>>(bsum, boff, rowptr);
        k_scan_add<<<NB, 256, 0, stream>>>(rowptr, boff, fill);   // fill := wcur
        k_scatter<<<(NNZn + 255) / 256, 256, 0, stream>>>(edge_rows, edge_cols,
                                                          edge_vals, fill, csr);
        k_wfrag<<<96, 256, 0, stream>>>(W, wfr);

        // transpose into level 0, then the 5 Chebyshev SpMMs
        k_transpose_h<<<Mn / 4, 256, 0, stream>>>(x, slot[0]);
        k_spmm_h<<<spmm_grid, 256, 0, stream>>>(slot[0], slot[0], slot[1],
                                                rowptr, csr, 1);
        k_spmm_h<<<spmm_grid, 256, 0, stream>>>(slot[1], slot[0], slot[2],
                                                rowptr, csr, 0);
        k_spmm_h<<<spmm_grid, 256, 0, stream>>>(slot[2], slot[1], slot[3],
                                                rowptr, csr, 0);
        k_spmm_h<<<spmm_grid, 256, 0, stream>>>(slot[3], slot[2], slot[4],
                                                rowptr, csr, 0);
        k_spmm_h<<<spmm_grid, 256, 0, stream>>>(slot[4], slot[3], slot[5],
                                                rowptr, csr, 0);
        // single-pass projection over all 6 levels (no out RMW)
        k_gemm_mfma<<<gemm_grid, 256, 0, stream>>>(xh, wfr, out);
    } else {
        // fp32 fallback: 3 rotating fp32 buffers + fp32 vector GEMM
        float* buf0 = (float*)(ws);
        float* buf1 = (float*)(ws + bufB);
        float* buf2 = (float*)(ws + 2 * bufB);
        int*   rowptr = (int*)(ws + 3 * bufB);
        int*   fill   = rowptr + (Mn + 4);
        int2*  csr    = (int2*)(fill + Mn);
        int*   bsum   = (int*)csr;
        int*   boff   = bsum + 256;
        hipMemsetAsync(fill, 0, Mn * sizeof(int), stream);
        k_hist<<<(NNZn + 255) / 256, 256, 0, stream>>>(edge_rows, fill);
        k_scan_part<<<NB, 256, 0, stream>>>(fill, rowptr, bsum);
        k_scan_bsums<<<1, 256, 0, stream>>>(bsum, boff, rowptr);
        k_scan_add<<<NB, 256, 0, stream>>>(rowptr, boff, fill);
        k_scatter<<<(NNZn + 255) / 256, 256, 0, stream>>>(edge_rows, edge_cols,
                                                          edge_vals, fill, csr);
        k_transpose_f<<<Mn, 512, 0, stream>>>(x, buf0);
        k_spmm_f32<<<Mn / 4, 256, 0, stream>>>((const float4*)buf0, (const float4*)buf0,
                                               (float4*)buf1, rowptr, csr, 1);
        k_gemm2<<<Mn / 4, 256, 0, stream>>>(buf0, buf1, W, out, 0, 1, 0);
        k_spmm_f32<<<Mn / 4, 256, 0, stream>>>((const float4*)buf1, (const float4*)buf0,
                                               (float4*)buf2, rowptr, csr, 0);
        k_spmm_f32<<<Mn / 4, 256, 0, stream>>>((const float4*)buf2, (const float4*)buf1,
                                               (float4*)buf0, rowptr, csr, 0);
        k_gemm2<<<Mn / 4, 256, 0, stream>>>(buf2, buf0, W, out, 2, 3, 1);
        k_spmm_f32<<<Mn / 4, 256, 0, stream>>>((const float4*)buf0, (const float4*)buf2,
                                               (float4*)buf1, rowptr, csr, 0);
        k_spmm_f32<<<Mn / 4, 256, 0, stream>>>((const float4*)buf1, (const float4*)buf0,
                                               (float4*)buf2, rowptr, csr, 0);
        k_gemm2<<<Mn / 4, 256, 0, stream>>>(buf1, buf2, W, out, 4, 5, 1);
    }
}

// Round 7
// 540.393 us; speedup vs baseline: 1.0226x; 1.0226x over previous
//
#include <hip/hip_runtime.h>

// Problem constants (MeshConv: B=8, M=40000, FIN=64, K=6, FOUT=64, NNZ=320000)
#define Mn    40000
#define Bn    8
#define FINn  64
#define Kn    6
#define FOUTn 64
#define NNZn  320000
#define Cn    512   // FIN*B values per level row; c = b*64 + f
#define NB    ((Mn + 255) / 256)   // scan blocks = 157
#define MT    (Mn / 64)            // 625 m-tiles for the GEMM

// Level layout (fp16): xh[lev][m][c] -- one row = 1KB contiguous.
// SpMM gathers one full 1KB row per edge (64 lanes x 16B, fully coalesced);
// GEMM reads 64-row x 128B tiles per (b, m-tile).

typedef _Float16 half8 __attribute__((ext_vector_type(8)));  // MFMA A/B frag
typedef __attribute__((ext_vector_type(4))) float floatx4;   // MFMA accumulator

__device__ __forceinline__ ushort f2h(float f) {
    _Float16 h = (_Float16)f;
    return *(ushort*)&h;
}

// async global->LDS, 16B per lane; dst must be wave-uniform base (HW adds lane*16)
__device__ __forceinline__ void gl_lds16(const ushort* g, ushort* l) {
    __builtin_amdgcn_global_load_lds(
        (const __attribute__((address_space(1))) unsigned int*)g,
        (__attribute__((address_space(3))) unsigned int*)l, 16, 0, 0);
}

// ---------------- CSR build ----------------

__global__ __launch_bounds__(256) void k_hist(const int* __restrict__ rows,
                                              int* __restrict__ cnt) {
    int e = blockIdx.x * 256 + threadIdx.x;
    if (e < NNZn) atomicAdd(&cnt[rows[e]], 1);
}

__global__ __launch_bounds__(256) void k_scan_part(const int* __restrict__ cnt,
                                                   int* __restrict__ rowptr,
                                                   int* __restrict__ bsum) {
    __shared__ int part[256];
    int tid = threadIdx.x;
    int r = blockIdx.x * 256 + tid;
    int v = (r < Mn) ? cnt[r] : 0;
    part[tid] = v;
    __syncthreads();
    for (int off = 1; off < 256; off <<= 1) {
        int t = (tid >= off) ? part[tid - off] : 0;
        __syncthreads();
        part[tid] += t;
        __syncthreads();
    }
    if (r < Mn) rowptr[r] = part[tid] - v;
    if (tid == 255) bsum[blockIdx.x] = part[255];
}

__global__ __launch_bounds__(256) void k_scan_bsums(const int* __restrict__ bsum,
                                                    int* __restrict__ boff,
                                                    int* __restrict__ rowptr) {
    __shared__ int part[256];
    int tid = threadIdx.x;
    int v = (tid < NB) ? bsum[tid] : 0;
    part[tid] = v;
    __syncthreads();
    for (int off = 1; off < 256; off <<= 1) {
        int t = (tid >= off) ? part[tid - off] : 0;
        __syncthreads();
        part[tid] += t;
        __syncthreads();
    }
    if (tid < NB) boff[tid] = part[tid] - v;
    if (tid == 255) rowptr[Mn] = part[255];
}

__global__ __launch_bounds__(256) void k_scan_add(int* __restrict__ rowptr,
                                                  const int* __restrict__ boff,
                                                  int* __restrict__ wcur) {
    int r = blockIdx.x * 256 + threadIdx.x;
    if (r < Mn) {
        int v = rowptr[r] + boff[blockIdx.x];
        rowptr[r] = v;
        wcur[r] = v;
    }
}

__global__ __launch_bounds__(256) void k_scatter(const int* __restrict__ rows,
                                                 const int* __restrict__ cols,
                                                 const float* __restrict__ vals,
                                                 int* __restrict__ wcur,
                                                 int2* __restrict__ csr) {
    int e = blockIdx.x * 256 + threadIdx.x;
    if (e < NNZn) {
        int p = atomicAdd(&wcur[rows[e]], 1);
        int2 cv; cv.x = cols[e]; cv.y = __float_as_int(vals[e]);
        csr[p] = cv;
    }
}

// ---------------- x -> x0 (fp16): transpose to [m][b*64+f] ----------------

__global__ __launch_bounds__(256) void k_transpose_h(const float* __restrict__ x,
                                                     ushort* __restrict__ x0h) {
    int m0 = blockIdx.x * 4;
    int t  = threadIdx.x;
#pragma unroll
    for (int k = 0; k < 2; ++k) {
        int i   = t + k * 256;       // 0..511
        int ml  = i >> 7;            // 0..3
        int rem = i & 127;
        int b   = rem >> 4;
        int fq  = (rem & 15) * 4;
        float4 a = *(const float4*)(x + ((size_t)b * Mn + m0 + ml) * 64 + fq);
        union { uint2 u; ushort h[4]; } s;
        s.h[0] = f2h(a.x); s.h[1] = f2h(a.y); s.h[2] = f2h(a.z); s.h[3] = f2h(a.w);
        *(uint2*)(x0h + (size_t)(m0 + ml) * Cn + b * 64 + fq) = s.u;
    }
}

// ---------------- SpMM (all-fp16 state) + Chebyshev recurrence ----------------
// R5 form (best measured): one row per wave, 64 lanes x 16B = one contiguous
// 1KB transaction per edge-gather; 8-deep unroll; xp issued early.

__device__ __forceinline__ void fmah8(float* a, uint4 g, float w) {
    union { uint4 u; _Float16 h[8]; } c; c.u = g;
#pragma unroll
    for (int i = 0; i < 8; ++i) a[i] += w * (float)c.h[i];
}

__global__ __launch_bounds__(256) void k_spmm_h(const ushort* __restrict__ xc,
                                                const ushort* __restrict__ xp,
                                                ushort* __restrict__ xn,
                                                const int* __restrict__ rowptr,
                                                const int2* __restrict__ csr,
                                                int first) {
    int t = threadIdx.x;
    int lane = t & 63;
    int m = blockIdx.x * 4 + (t >> 6);
    const uint4* xc4 = (const uint4*)xc;      // row = 64 uint4 (512 halves)
    uint4 v = xc4[(size_t)m * 64 + lane];
    uint4 p;
    if (!first) p = ((const uint4*)xp)[(size_t)m * 64 + lane];   // early issue
    float a[8];
    { union { uint4 u; _Float16 h[8]; } c; c.u = v;
#pragma unroll
      for (int i = 0; i < 8; ++i) a[i] = -(float)c.h[i]; }

    int e = rowptr[m], end = rowptr[m + 1];
    for (; e + 8 <= end; e += 8) {
        int2 cv[8];
#pragma unroll
        for (int i = 0; i < 8; ++i) cv[i] = csr[e + i];
        uint4 g[8];
#pragma unroll
        for (int i = 0; i < 8; ++i) g[i] = xc4[(size_t)cv[i].x * 64 + lane];
#pragma unroll
        for (int i = 0; i < 8; ++i) fmah8(a, g[i], __int_as_float(cv[i].y));
    }
    for (; e + 4 <= end; e += 4) {
        int2 cv0 = csr[e],     cv1 = csr[e + 1];
        int2 cv2 = csr[e + 2], cv3 = csr[e + 3];
        uint4 g0 = xc4[(size_t)cv0.x * 64 + lane];
        uint4 g1 = xc4[(size_t)cv1.x * 64 + lane];
        uint4 g2 = xc4[(size_t)cv2.x * 64 + lane];
        uint4 g3 = xc4[(size_t)cv3.x * 64 + lane];
        fmah8(a, g0, __int_as_float(cv0.y));
        fmah8(a, g1, __int_as_float(cv1.y));
        fmah8(a, g2, __int_as_float(cv2.y));
        fmah8(a, g3, __int_as_float(cv3.y));
    }
    for (; e < end; ++e) {
        int2 cv = csr[e];
        uint4 g = xc4[(size_t)cv.x * 64 + lane];
        fmah8(a, g, __int_as_float(cv.y));
    }

    if (!first) {
        union { uint4 u; _Float16 h[8]; } c; c.u = p;
#pragma unroll
        for (int i = 0; i < 8; ++i) a[i] = 2.f * a[i] - (float)c.h[i];
    }
    union { uint4 u; _Float16 h[8]; } s;
#pragma unroll
    for (int i = 0; i < 8; ++i) s.h[i] = (_Float16)a[i];
    ((uint4*)xn)[(size_t)m * 64 + lane] = s.u;
}

// ---------------- W -> MFMA B-fragment pre-swizzle (fp16) ----------------

__global__ __launch_bounds__(256) void k_wfrag(const float* __restrict__ W,
                                               ushort* __restrict__ wfrag) {
    int idx = blockIdx.x * 256 + threadIdx.x;   // 12*4*64*8 = 24576
    if (idx >= 12 * 4 * 64 * 8) return;
    int j    = idx & 7;
    int lane = (idx >> 3) & 63;
    int n    = (idx >> 9) & 3;
    int kk   = idx >> 11;
    int k    = (lane >> 4) * 8 + j;
    int lev  = kk >> 1;
    int f    = (kk & 1) * 32 + k;
    int fo   = n * 16 + (lane & 15);
    wfrag[idx] = f2h(W[(f * Kn + lev) * FOUTn + fo]);
}

// ---------------- MFMA projection GEMM (fp16 inputs, fp32 acc) ----------------
// Per-wave self-contained, double-buffered, ZERO barriers:
// wave wv stages ONLY the 16 rows it reads (rows m0+wv*16..+15) into its own
// 2KB LDS region (2 x global_load_lds per level, 2 level-buffers). Sync is a
// per-wave counted s_waitcnt vmcnt(2) -- never drained to 0 mid-loop -- so
// stage(lev+2) stays in flight under lev's MFMAs (R2's interleave, but async
// and barrier-free; R6's 48KB single-barrier burst ran at 28% occupancy).

__global__ __launch_bounds__(256, 4) void k_gemm_mfma(const ushort* __restrict__ xh,
                                                      const ushort* __restrict__ wfrag,
                                                      float* __restrict__ out) {
    __shared__ __align__(16) ushort As[2][4][1024];   // [buf][wave][16 rows x 64] = 16KB
    int t     = threadIdx.x;
    int wv    = t >> 6;
    int lane  = t & 63;
    int q     = lane >> 4, r = lane & 15;
    int mtile = blockIdx.x % MT;
    int b     = blockIdx.x / MT;
    int m0    = mtile * 64;

    const size_t lstrideH = (size_t)Mn * Cn;   // level stride in halves

    // staging: lane covers local row srow = lane>>3 (and srow+8 via gsB);
    // global granule pre-XOR'd so the linear LDS dest ends up swizzled.
    int srow = lane >> 3;
    int gsw  = (lane & 7) ^ (srow & 7);        // (srow+8)&7 == srow&7
    const ushort* gsA = xh + (size_t)(m0 + wv * 16 + srow) * Cn + b * 64 + gsw * 8;
    const ushort* gsB = gsA + 8 * (size_t)Cn;
    int swz = r & 7;

    floatx4 acc0 = (floatx4)0.f, acc1 = (floatx4)0.f;
    floatx4 acc2 = (floatx4)0.f, acc3 = (floatx4)0.f;

#define STAGE(lev, buf) do {                                       \
        gl_lds16(gsA + (size_t)(lev) * lstrideH, &As[buf][wv][0]);   \
        gl_lds16(gsB + (size_t)(lev) * lstrideH, &As[buf][wv][512]); \
    } while (0)

#define MC(kkg, af) do {                                                              \
        const ushort* wf = wfrag + ((size_t)((kkg) * 4) * 64 + lane) * 8;             \
        acc0 = __builtin_amdgcn_mfma_f32_16x16x32_f16(af, *(const half8*)(wf),        acc0, 0, 0, 0); \
        acc1 = __builtin_amdgcn_mfma_f32_16x16x32_f16(af, *(const half8*)(wf + 512),  acc1, 0, 0, 0); \
        acc2 = __builtin_amdgcn_mfma_f32_16x16x32_f16(af, *(const half8*)(wf + 1024), acc2, 0, 0, 0); \
        acc3 = __builtin_amdgcn_mfma_f32_16x16x32_f16(af, *(const half8*)(wf + 1536), acc3, 0, 0, 0); \
    } while (0)

#define LEVEL(lev, buf, VMSTR) do {                                                   \
        asm volatile("s_waitcnt vmcnt(" VMSTR ")" ::: "memory");                      \
        __builtin_amdgcn_sched_barrier(0);                                            \
        half8 af0 = *(const half8*)&As[buf][wv][r * 64 + (((0 + q) ^ swz) << 3)];     \
        half8 af1 = *(const half8*)&As[buf][wv][r * 64 + (((4 + q) ^ swz) << 3)];     \
        asm volatile("s_waitcnt lgkmcnt(0)" ::: "memory");                            \
        __builtin_amdgcn_sched_barrier(0);                                            \
        if ((lev) < 4) STAGE((lev) + 2, buf);                                         \
        MC((lev) * 2, af0);                                                           \
        MC((lev) * 2 + 1, af1);                                                       \
    } while (0)

    STAGE(0, 0);
    STAGE(1, 1);
    LEVEL(0, 0, "2");
    LEVEL(1, 1, "2");
    LEVEL(2, 0, "2");
    LEVEL(3, 1, "2");
    LEVEL(4, 0, "2");
    LEVEL(5, 1, "0");

#undef LEVEL
#undef MC
#undef STAGE

    // C/D layout: col = lane&15, row = (lane>>4)*4 + reg
    size_t obase = ((size_t)b * Mn + m0 + wv * 16) * FOUTn;
#pragma unroll
    for (int n = 0; n < 4; ++n) {
        floatx4 av = (n == 0) ? acc0 : (n == 1) ? acc1 : (n == 2) ? acc2 : acc3;
#pragma unroll
        for (int reg = 0; reg < 4; ++reg) {
            int orow = q * 4 + reg;
            out[obase + (size_t)orow * FOUTn + n * 16 + r] = av[reg];
        }
    }
}

// ---------------- fallback fp32 kernels (ws too small; not expected) ----------------

__global__ __launch_bounds__(512) void k_transpose_f(const float* __restrict__ x,
                                                     float* __restrict__ x0) {
    int m = blockIdx.x, t = threadIdx.x;
    int b = t >> 6, f = t & 63;
    x0[(size_t)m * Cn + t] = x[((size_t)b * Mn + m) * 64 + f];
}

__global__ __launch_bounds__(256) void k_spmm_f32(const float4* __restrict__ xc,
                                                  const float4* __restrict__ xp,
                                                  float4* __restrict__ xn,
                                                  const int* __restrict__ rowptr,
                                                  const int2* __restrict__ csr,
                                                  int first) {
    int t = threadIdx.x;
    int lane = t & 63;
    int m = blockIdx.x * 4 + (t >> 6);
    size_t rb = (size_t)m * 128;
    float4 v0 = xc[rb + lane];
    float4 v1 = xc[rb + 64 + lane];
    float4 a0 = make_float4(-v0.x, -v0.y, -v0.z, -v0.w);
    float4 a1 = make_float4(-v1.x, -v1.y, -v1.z, -v1.w);
    int e = rowptr[m], end = rowptr[m + 1];
    for (; e < end; ++e) {
        int2 cv = csr[e];
        float w = __int_as_float(cv.y);
        const float4* r = xc + (size_t)cv.x * 128;
        float4 g0 = r[lane], g1 = r[64 + lane];
        a0.x += w * g0.x; a0.y += w * g0.y; a0.z += w * g0.z; a0.w += w * g0.w;
        a1.x += w * g1.x; a1.y += w * g1.y; a1.z += w * g1.z; a1.w += w * g1.w;
    }
    if (!first) {
        float4 p0 = xp[rb + lane];
        float4 p1 = xp[rb + 64 + lane];
        a0.x = 2.f * a0.x - p0.x; a0.y = 2.f * a0.y - p0.y;
        a0.z = 2.f * a0.z - p0.z; a0.w = 2.f * a0.w - p0.w;
        a1.x = 2.f * a1.x - p1.x; a1.y = 2.f * a1.y - p1.y;
        a1.z = 2.f * a1.z - p1.z; a1.w = 2.f * a1.w - p1.w;
    }
    xn[rb + lane] = a0;
    xn[rb + 64 + lane] = a1;
}

__global__ __launch_bounds__(256) void k_gemm2(const float* __restrict__ xa,
                                               const float* __restrict__ xb,
                                               const float* __restrict__ W,
                                               float* __restrict__ out,
                                               int ka, int kb, int accum) {
    __shared__ __align__(16) float Wa[64 * 64];
    __shared__ __align__(16) float Wb[64 * 64];
    __shared__ __align__(16) float xsa[4 * Cn];
    __shared__ __align__(16) float xsb[4 * Cn];
    int t = threadIdx.x;
    size_t m0 = (size_t)blockIdx.x * 4;
    for (int i = t; i < 4096; i += 256) {
        int f = i >> 6, fo = i & 63;
        Wa[i] = W[(f * Kn + ka) * FOUTn + fo];
        Wb[i] = W[(f * Kn + kb) * FOUTn + fo];
    }
    for (int i = t; i < 4 * Cn; i += 256) {
        xsa[i] = xa[m0 * Cn + i];
        xsb[i] = xb[m0 * Cn + i];
    }
    __syncthreads();
    int fo  = (t & 15) * 4;
    int idx = t >> 4;
    int m   = idx & 3;
    int bq  = idx >> 2;
    float4 acc0 = make_float4(0.f, 0.f, 0.f, 0.f);
    float4 acc1 = make_float4(0.f, 0.f, 0.f, 0.f);
    for (int f = 0; f < 64; ++f) {
        float4 wa = *(const float4*)&Wa[f * 64 + fo];
        float a0 = xsa[m * Cn + bq * 64 + f];
        float a1 = xsa[m * Cn + (bq + 4) * 64 + f];
        acc0.x += a0 * wa.x; acc0.y += a0 * wa.y; acc0.z += a0 * wa.z; acc0.w += a0 * wa.w;
        acc1.x += a1 * wa.x; acc1.y += a1 * wa.y; acc1.z += a1 * wa.z; acc1.w += a1 * wa.w;
        float4 wb = *(const float4*)&Wb[f * 64 + fo];
        float b0 = xsb[m * Cn + bq * 64 + f];
        float b1 = xsb[m * Cn + (bq + 4) * 64 + f];
        acc0.x += b0 * wb.x; acc0.y += b0 * wb.y; acc0.z += b0 * wb.z; acc0.w += b0 * wb.w;
        acc1.x += b1 * wb.x; acc1.y += b1 * wb.y; acc1.z += b1 * wb.z; acc1.w += b1 * wb.w;
    }
    size_t o0 = (((size_t)bq * Mn) + (m0 + m)) * FOUTn + fo;
    size_t o1 = (((size_t)(bq + 4) * Mn) + (m0 + m)) * FOUTn + fo;
    float4* out4_0 = (float4*)&out[o0];
    float4* out4_1 = (float4*)&out[o1];
    if (accum) {
        float4 c0 = *out4_0, c1 = *out4_1;
        acc0.x += c0.x; acc0.y += c0.y; acc0.z += c0.z; acc0.w += c0.w;
        acc1.x += c1.x; acc1.y += c1.y; acc1.z += c1.z; acc1.w += c1.w;
    }
    *out4_0 = acc0;
    *out4_1 = acc1;
}

// ---------------- launch ----------------

extern "C" void kernel_launch(void* const* d_in, const int* in_sizes, int n_in,
                              void* d_out, int out_size, void* d_ws, size_t ws_size,
                              hipStream_t stream) {
    const float* x         = (const float*)d_in[0];
    const float* edge_vals = (const float*)d_in[1];
    const float* W         = (const float*)d_in[2];
    const int*   edge_rows = (const int*)d_in[3];
    const int*   edge_cols = (const int*)d_in[4];
    float* out = (float*)d_out;

    char* ws = (char*)d_ws;
    const size_t bufB = (size_t)Mn * Cn * sizeof(float);   // 81.92 MB fp32 level
    const size_t bufH = (size_t)Mn * Cn * sizeof(ushort);  // 40.96 MB fp16 level
    const size_t wfB  = 12 * 4 * 64 * 8 * sizeof(ushort);  // 48 KB
    const size_t csrB = (size_t)(Mn + 4 + Mn) * 4 + (size_t)NNZn * 8;  // ~2.9 MB

    const int spmm_grid = Mn / 4;      // 10000
    const int gemm_grid = MT * 8;      // 5000, b-major

    // primary plan: 6 fp16 level slots (248.69 MB total), layout [lev][m][c]
    if (ws_size >= 6 * bufH + wfB + csrB) {
        ushort* xh  = (ushort*)ws;                       // slot l at xh + l*Mn*Cn
        ushort* wfr = (ushort*)(ws + 6 * bufH);
        int*    rowptr = (int*)(ws + 6 * bufH + wfB);
        int*    fill   = rowptr + (Mn + 4);              // doubles as wcur
        int2*   csr    = (int2*)(fill + Mn);
        int*    bsum   = (int*)csr;                      // scan scratch in csr buf
        int*    boff   = bsum + 256;
        ushort* slot[6];
        for (int l = 0; l < 6; ++l) slot[l] = xh + (size_t)l * Mn * Cn;

        // CSR build (every call; ws re-poisoned by harness)
        hipMemsetAsync(fill, 0, Mn * sizeof(int), stream);
        k_hist<<<(NNZn + 255) / 256, 256, 0, stream>>>(edge_rows, fill);
        k_scan_part<<<NB, 256, 0, stream>>>(fill, rowptr, bsum);
        k_scan_bsums<<<1, 256, 0, stream>>>(bsum, boff, rowptr);
        k_scan_add<<<NB, 256, 0, stream>>>(rowptr, boff, fill);   // fill := wcur
        k_scatter<<<(NNZn + 255) / 256, 256, 0, stream>>>(edge_rows, edge_cols,
                                                          edge_vals, fill, csr);
        k_wfrag<<<96, 256, 0, stream>>>(W, wfr);

        // transpose into level 0, then the 5 Chebyshev SpMMs
        k_transpose_h<<<Mn / 4, 256, 0, stream>>>(x, slot[0]);
        k_spmm_h<<<spmm_grid, 256, 0, stream>>>(slot[0], slot[0], slot[1],
                                                rowptr, csr, 1);
        k_spmm_h<<<spmm_grid, 256, 0, stream>>>(slot[1], slot[0], slot[2],
                                                rowptr, csr, 0);
        k_spmm_h<<<spmm_grid, 256, 0, stream>>>(slot[2], slot[1], slot[3],
                                                rowptr, csr, 0);
        k_spmm_h<<<spmm_grid, 256, 0, stream>>>(slot[3], slot[2], slot[4],
                                                rowptr, csr, 0);
        k_spmm_h<<<spmm_grid, 256, 0, stream>>>(slot[4], slot[3], slot[5],
                                                rowptr, csr, 0);
        // single-pass projection over all 6 levels (no out RMW)
        k_gemm_mfma<<<gemm_grid, 256, 0, stream>>>(xh, wfr, out);
    } else {
        // fp32 fallback: 3 rotating fp32 buffers + fp32 vector GEMM
        float* buf0 = (float*)(ws);
        float* buf1 = (float*)(ws + bufB);
        float* buf2 = (float*)(ws + 2 * bufB);
        int*   rowptr = (int*)(ws + 3 * bufB);
        int*   fill   = rowptr + (Mn + 4);
        int2*  csr    = (int2*)(fill + Mn);
        int*   bsum   = (int*)csr;
        int*   boff   = bsum + 256;
        hipMemsetAsync(fill, 0, Mn * sizeof(int), stream);
        k_hist<<<(NNZn + 255) / 256, 256, 0, stream>>>(edge_rows, fill);
        k_scan_part<<<NB, 256, 0, stream>>>(fill, rowptr, bsum);
        k_scan_bsums<<<1, 256, 0, stream>>>(bsum, boff, rowptr);
        k_scan_add<<<NB, 256, 0, stream>>>(rowptr, boff, fill);
        k_scatter<<<(NNZn + 255) / 256, 256, 0, stream>>>(edge_rows, edge_cols,
                                                          edge_vals, fill, csr);
        k_transpose_f<<<Mn, 512, 0, stream>>>(x, buf0);
        k_spmm_f32<<<Mn / 4, 256, 0, stream>>>((const float4*)buf0, (const float4*)buf0,
                                               (float4*)buf1, rowptr, csr, 1);
        k_gemm2<<<Mn / 4, 256, 0, stream>>>(buf0, buf1, W, out, 0, 1, 0);
        k_spmm_f32<<<Mn / 4, 256, 0, stream>>>((const float4*)buf1, (const float4*)buf0,
                                               (float4*)buf2, rowptr, csr, 0);
        k_spmm_f32<<<Mn / 4, 256, 0, stream>>>((const float4*)buf2, (const float4*)buf1,
                                               (float4*)buf0, rowptr, csr, 0);
        k_gemm2<<<Mn / 4, 256, 0, stream>>>(buf2, buf0, W, out, 2, 3, 1);
        k_spmm_f32<<<Mn / 4, 256, 0, stream>>>((const float4*)buf0, (const float4*)buf2,
                                               (float4*)buf1, rowptr, csr, 0);
        k_spmm_f32<<<Mn / 4, 256, 0, stream>>>((const float4*)buf1, (const float4*)buf0,
                                               (float4*)buf2, rowptr, csr, 0);
        k_gemm2<<<Mn / 4, 256, 0, stream>>>(buf1, buf2, W, out, 4, 5, 1);
    }
}

// Round 8
// 521.627 us; speedup vs baseline: 1.0594x; 1.0360x over previous
//
#include <hip/hip_runtime.h>

// Problem constants (MeshConv: B=8, M=40000, FIN=64, K=6, FOUT=64, NNZ=320000)
#define Mn    40000
#define Bn    8
#define FINn  64
#define Kn    6
#define FOUTn 64
#define NNZn  320000
#define Cn    512   // FIN*B values per level row; c = b*64 + f
#define NB    ((Mn + 255) / 256)   // scan blocks = 157
#define MT    (Mn / 64)            // 625 m-tiles for the GEMM

// Level layout (fp16): xh[lev][m][c] -- one row = 1KB contiguous.
// SpMM gathers one full 1KB row per edge (64 lanes x 16B, fully coalesced);
// GEMM reads 64-row x 128B tiles per (b, m-tile).

typedef _Float16 half8 __attribute__((ext_vector_type(8)));  // MFMA A/B frag
typedef __attribute__((ext_vector_type(4))) float floatx4;   // MFMA accumulator

__device__ __forceinline__ ushort f2h(float f) {
    _Float16 h = (_Float16)f;
    return *(ushort*)&h;
}

// async global->LDS, 16B per lane; dst must be wave-uniform base (HW adds lane*16)
__device__ __forceinline__ void gl_lds16(const ushort* g, ushort* l) {
    __builtin_amdgcn_global_load_lds(
        (const __attribute__((address_space(1))) unsigned int*)g,
        (__attribute__((address_space(3))) unsigned int*)l, 16, 0, 0);
}

// ---------------- CSR build ----------------

__global__ __launch_bounds__(256) void k_hist(const int* __restrict__ rows,
                                              int* __restrict__ cnt) {
    int e = blockIdx.x * 256 + threadIdx.x;
    if (e < NNZn) atomicAdd(&cnt[rows[e]], 1);
}

__global__ __launch_bounds__(256) void k_scan_part(const int* __restrict__ cnt,
                                                   int* __restrict__ rowptr,
                                                   int* __restrict__ bsum) {
    __shared__ int part[256];
    int tid = threadIdx.x;
    int r = blockIdx.x * 256 + tid;
    int v = (r < Mn) ? cnt[r] : 0;
    part[tid] = v;
    __syncthreads();
    for (int off = 1; off < 256; off <<= 1) {
        int t = (tid >= off) ? part[tid - off] : 0;
        __syncthreads();
        part[tid] += t;
        __syncthreads();
    }
    if (r < Mn) rowptr[r] = part[tid] - v;
    if (tid == 255) bsum[blockIdx.x] = part[255];
}

__global__ __launch_bounds__(256) void k_scan_bsums(const int* __restrict__ bsum,
                                                    int* __restrict__ boff,
                                                    int* __restrict__ rowptr) {
    __shared__ int part[256];
    int tid = threadIdx.x;
    int v = (tid < NB) ? bsum[tid] : 0;
    part[tid] = v;
    __syncthreads();
    for (int off = 1; off < 256; off <<= 1) {
        int t = (tid >= off) ? part[tid - off] : 0;
        __syncthreads();
        part[tid] += t;
        __syncthreads();
    }
    if (tid < NB) boff[tid] = part[tid] - v;
    if (tid == 255) rowptr[Mn] = part[255];
}

__global__ __launch_bounds__(256) void k_scan_add(int* __restrict__ rowptr,
                                                  const int* __restrict__ boff,
                                                  int* __restrict__ wcur) {
    int r = blockIdx.x * 256 + threadIdx.x;
    if (r < Mn) {
        int v = rowptr[r] + boff[blockIdx.x];
        rowptr[r] = v;
        wcur[r] = v;
    }
}

__global__ __launch_bounds__(256) void k_scatter(const int* __restrict__ rows,
                                                 const int* __restrict__ cols,
                                                 const float* __restrict__ vals,
                                                 int* __restrict__ wcur,
                                                 int2* __restrict__ csr) {
    int e = blockIdx.x * 256 + threadIdx.x;
    if (e < NNZn) {
        int p = atomicAdd(&wcur[rows[e]], 1);
        int2 cv; cv.x = cols[e]; cv.y = __float_as_int(vals[e]);
        csr[p] = cv;
    }
}

// ---------------- x -> x0 (fp16): transpose to [m][b*64+f] ----------------

__global__ __launch_bounds__(256) void k_transpose_h(const float* __restrict__ x,
                                                     ushort* __restrict__ x0h) {
    int m0 = blockIdx.x * 4;
    int t  = threadIdx.x;
#pragma unroll
    for (int k = 0; k < 2; ++k) {
        int i   = t + k * 256;       // 0..511
        int ml  = i >> 7;            // 0..3
        int rem = i & 127;
        int b   = rem >> 4;
        int fq  = (rem & 15) * 4;
        float4 a = *(const float4*)(x + ((size_t)b * Mn + m0 + ml) * 64 + fq);
        union { uint2 u; ushort h[4]; } s;
        s.h[0] = f2h(a.x); s.h[1] = f2h(a.y); s.h[2] = f2h(a.z); s.h[3] = f2h(a.w);
        *(uint2*)(x0h + (size_t)(m0 + ml) * Cn + b * 64 + fq) = s.u;
    }
}

// ---------------- SpMM (all-fp16 state) + Chebyshev recurrence ----------------
// R5 form (best measured): one row per wave, 64 lanes x 16B = one contiguous
// 1KB transaction per edge-gather; 8-deep unroll; xp issued early.

__device__ __forceinline__ void fmah8(float* a, uint4 g, float w) {
    union { uint4 u; _Float16 h[8]; } c; c.u = g;
#pragma unroll
    for (int i = 0; i < 8; ++i) a[i] += w * (float)c.h[i];
}

__global__ __launch_bounds__(256) void k_spmm_h(const ushort* __restrict__ xc,
                                                const ushort* __restrict__ xp,
                                                ushort* __restrict__ xn,
                                                const int* __restrict__ rowptr,
                                                const int2* __restrict__ csr,
                                                int first) {
    int t = threadIdx.x;
    int lane = t & 63;
    int m = blockIdx.x * 4 + (t >> 6);
    const uint4* xc4 = (const uint4*)xc;      // row = 64 uint4 (512 halves)
    uint4 v = xc4[(size_t)m * 64 + lane];
    uint4 p;
    if (!first) p = ((const uint4*)xp)[(size_t)m * 64 + lane];   // early issue
    float a[8];
    { union { uint4 u; _Float16 h[8]; } c; c.u = v;
#pragma unroll
      for (int i = 0; i < 8; ++i) a[i] = -(float)c.h[i]; }

    int e = rowptr[m], end = rowptr[m + 1];
    for (; e + 8 <= end; e += 8) {
        int2 cv[8];
#pragma unroll
        for (int i = 0; i < 8; ++i) cv[i] = csr[e + i];
        uint4 g[8];
#pragma unroll
        for (int i = 0; i < 8; ++i) g[i] = xc4[(size_t)cv[i].x * 64 + lane];
#pragma unroll
        for (int i = 0; i < 8; ++i) fmah8(a, g[i], __int_as_float(cv[i].y));
    }
    for (; e + 4 <= end; e += 4) {
        int2 cv0 = csr[e],     cv1 = csr[e + 1];
        int2 cv2 = csr[e + 2], cv3 = csr[e + 3];
        uint4 g0 = xc4[(size_t)cv0.x * 64 + lane];
        uint4 g1 = xc4[(size_t)cv1.x * 64 + lane];
        uint4 g2 = xc4[(size_t)cv2.x * 64 + lane];
        uint4 g3 = xc4[(size_t)cv3.x * 64 + lane];
        fmah8(a, g0, __int_as_float(cv0.y));
        fmah8(a, g1, __int_as_float(cv1.y));
        fmah8(a, g2, __int_as_float(cv2.y));
        fmah8(a, g3, __int_as_float(cv3.y));
    }
    for (; e < end; ++e) {
        int2 cv = csr[e];
        uint4 g = xc4[(size_t)cv.x * 64 + lane];
        fmah8(a, g, __int_as_float(cv.y));
    }

    if (!first) {
        union { uint4 u; _Float16 h[8]; } c; c.u = p;
#pragma unroll
        for (int i = 0; i < 8; ++i) a[i] = 2.f * a[i] - (float)c.h[i];
    }
    union { uint4 u; _Float16 h[8]; } s;
#pragma unroll
    for (int i = 0; i < 8; ++i) s.h[i] = (_Float16)a[i];
    ((uint4*)xn)[(size_t)m * 64 + lane] = s.u;
}

// ---------------- W -> MFMA B-fragment pre-swizzle (fp16) ----------------

__global__ __launch_bounds__(256) void k_wfrag(const float* __restrict__ W,
                                               ushort* __restrict__ wfrag) {
    int idx = blockIdx.x * 256 + threadIdx.x;   // 12*4*64*8 = 24576
    if (idx >= 12 * 4 * 64 * 8) return;
    int j    = idx & 7;
    int lane = (idx >> 3) & 63;
    int n    = (idx >> 9) & 3;
    int kk   = idx >> 11;
    int k    = (lane >> 4) * 8 + j;
    int lev  = kk >> 1;
    int f    = (kk & 1) * 32 + k;
    int fo   = n * 16 + (lane & 15);
    wfrag[idx] = f2h(W[(f * Kn + lev) * FOUTn + fo]);
}

// ---------------- MFMA projection GEMM (fp16 inputs, fp32 acc) ----------------
// Waves split by FO (wave wv owns fo-column n=wv): each wave needs only 12
// B-fragments for the ENTIRE kernel -> loaded ONCE into 12 named half8 regs
// (48 VGPRs, zero wfrag reloads; R7 streamed 48KB/wave = 960MB of L1-missing
// wfrag traffic, one load-chain per MFMA -- the residual latency).
// Shared A-tile (64 rows x 1 level = 8KB) double-buffered via global_load_lds
// with XOR-swizzled source granule; 2 barriers/level; stage(lev+2) issued
// after the read-done barrier. Inner loop = pure ds_read_b128 + MFMA.

__global__ __launch_bounds__(256, 4) void k_gemm_mfma(const ushort* __restrict__ xh,
                                                      const ushort* __restrict__ wfrag,
                                                      float* __restrict__ out) {
    __shared__ __align__(16) ushort As[2][4096];   // [buf][64 rows x 64 halves] = 16KB
    int t     = threadIdx.x;
    int wv    = t >> 6;
    int lane  = t & 63;
    int q     = lane >> 4, r = lane & 15;
    int mtile = blockIdx.x % MT;
    int b     = blockIdx.x / MT;
    int m0    = mtile * 64;
    int swz   = r & 7;

    const size_t lstrideH = (size_t)Mn * Cn;   // level stride in halves

    // B-fragments: wave wv's fo-column, all 12 K-chunks, register-resident.
    const ushort* wfb = wfrag + ((size_t)wv * 64 + lane) * 8;   // + kkg*2048
    half8 wf0  = *(const half8*)(wfb);
    half8 wf1  = *(const half8*)(wfb + 1 * 2048);
    half8 wf2  = *(const half8*)(wfb + 2 * 2048);
    half8 wf3  = *(const half8*)(wfb + 3 * 2048);
    half8 wf4  = *(const half8*)(wfb + 4 * 2048);
    half8 wf5  = *(const half8*)(wfb + 5 * 2048);
    half8 wf6  = *(const half8*)(wfb + 6 * 2048);
    half8 wf7  = *(const half8*)(wfb + 7 * 2048);
    half8 wf8  = *(const half8*)(wfb + 8 * 2048);
    half8 wf9  = *(const half8*)(wfb + 9 * 2048);
    half8 wf10 = *(const half8*)(wfb + 10 * 2048);
    half8 wf11 = *(const half8*)(wfb + 11 * 2048);

    // staging: wave wv covers rows [wv*8, wv*8+8) and [32+wv*8, ...) per call;
    // global granule pre-XOR'd so the linear LDS dest ends up swizzled.
    int srow = wv * 8 + (lane >> 3);
    int gsw  = (lane & 7) ^ (srow & 7);        // (srow+32)&7 == srow&7
    const ushort* gsA = xh + (size_t)(m0 + srow) * Cn + b * 64 + gsw * 8;
    const ushort* gsB = gsA + 32 * (size_t)Cn;

    floatx4 acc0 = (floatx4)0.f, acc1 = (floatx4)0.f;
    floatx4 acc2 = (floatx4)0.f, acc3 = (floatx4)0.f;

#define STAGE(lev, buf) do {                                          \
        gl_lds16(gsA + (size_t)(lev) * lstrideH, &As[buf][wv * 512]); \
        gl_lds16(gsB + (size_t)(lev) * lstrideH, &As[buf][2048 + wv * 512]); \
    } while (0)

    // A-fragment: rows sub*16 + r; (sub*16+r)&7 == r&7 == swz
#define AF(buf, sub, half) \
    (*(const half8*)&As[buf][((sub) * 16 + r) * 64 + (((((half) * 4) + q) ^ swz) << 3)])

#define LEVEL(lev, buf, VMSTR, WFA, WFB) do {                                         \
        asm volatile("s_waitcnt vmcnt(" VMSTR ")" ::: "memory");                      \
        __syncthreads();                                                              \
        half8 a00 = AF(buf, 0, 0); half8 a10 = AF(buf, 1, 0);                         \
        half8 a20 = AF(buf, 2, 0); half8 a30 = AF(buf, 3, 0);                         \
        half8 a01 = AF(buf, 0, 1); half8 a11 = AF(buf, 1, 1);                         \
        half8 a21 = AF(buf, 2, 1); half8 a31 = AF(buf, 3, 1);                         \
        acc0 = __builtin_amdgcn_mfma_f32_16x16x32_f16(a00, WFA, acc0, 0, 0, 0);       \
        acc1 = __builtin_amdgcn_mfma_f32_16x16x32_f16(a10, WFA, acc1, 0, 0, 0);       \
        acc2 = __builtin_amdgcn_mfma_f32_16x16x32_f16(a20, WFA, acc2, 0, 0, 0);       \
        acc3 = __builtin_amdgcn_mfma_f32_16x16x32_f16(a30, WFA, acc3, 0, 0, 0);       \
        acc0 = __builtin_amdgcn_mfma_f32_16x16x32_f16(a01, WFB, acc0, 0, 0, 0);       \
        acc1 = __builtin_amdgcn_mfma_f32_16x16x32_f16(a11, WFB, acc1, 0, 0, 0);       \
        acc2 = __builtin_amdgcn_mfma_f32_16x16x32_f16(a21, WFB, acc2, 0, 0, 0);       \
        acc3 = __builtin_amdgcn_mfma_f32_16x16x32_f16(a31, WFB, acc3, 0, 0, 0);       \
        __syncthreads();                                                              \
        if ((lev) < 4) STAGE((lev) + 2, buf);                                         \
    } while (0)

    STAGE(0, 0);
    STAGE(1, 1);
    LEVEL(0, 0, "2", wf0,  wf1);
    LEVEL(1, 1, "2", wf2,  wf3);
    LEVEL(2, 0, "2", wf4,  wf5);
    LEVEL(3, 1, "2", wf6,  wf7);
    LEVEL(4, 0, "2", wf8,  wf9);
    LEVEL(5, 1, "0", wf10, wf11);

#undef LEVEL
#undef AF
#undef STAGE

    // C/D layout: col = lane&15 (within this wave's fo-block n=wv),
    // row = (lane>>4)*4 + reg; sub-tile sub covers rows m0+sub*16..+15.
#pragma unroll
    for (int sub = 0; sub < 4; ++sub) {
        floatx4 av = (sub == 0) ? acc0 : (sub == 1) ? acc1 : (sub == 2) ? acc2 : acc3;
#pragma unroll
        for (int reg = 0; reg < 4; ++reg) {
            size_t o = ((size_t)b * Mn + m0 + sub * 16 + q * 4 + reg) * FOUTn
                     + wv * 16 + r;
            out[o] = av[reg];
        }
    }
}

// ---------------- fallback fp32 kernels (ws too small; not expected) ----------------

__global__ __launch_bounds__(512) void k_transpose_f(const float* __restrict__ x,
                                                     float* __restrict__ x0) {
    int m = blockIdx.x, t = threadIdx.x;
    int b = t >> 6, f = t & 63;
    x0[(size_t)m * Cn + t] = x[((size_t)b * Mn + m) * 64 + f];
}

__global__ __launch_bounds__(256) void k_spmm_f32(const float4* __restrict__ xc,
                                                  const float4* __restrict__ xp,
                                                  float4* __restrict__ xn,
                                                  const int* __restrict__ rowptr,
                                                  const int2* __restrict__ csr,
                                                  int first) {
    int t = threadIdx.x;
    int lane = t & 63;
    int m = blockIdx.x * 4 + (t >> 6);
    size_t rb = (size_t)m * 128;
    float4 v0 = xc[rb + lane];
    float4 v1 = xc[rb + 64 + lane];
    float4 a0 = make_float4(-v0.x, -v0.y, -v0.z, -v0.w);
    float4 a1 = make_float4(-v1.x, -v1.y, -v1.z, -v1.w);
    int e = rowptr[m], end = rowptr[m + 1];
    for (; e < end; ++e) {
        int2 cv = csr[e];
        float w = __int_as_float(cv.y);
        const float4* r = xc + (size_t)cv.x * 128;
        float4 g0 = r[lane], g1 = r[64 + lane];
        a0.x += w * g0.x; a0.y += w * g0.y; a0.z += w * g0.z; a0.w += w * g0.w;
        a1.x += w * g1.x; a1.y += w * g1.y; a1.z += w * g1.z; a1.w += w * g1.w;
    }
    if (!first) {
        float4 p0 = xp[rb + lane];
        float4 p1 = xp[rb + 64 + lane];
        a0.x = 2.f * a0.x - p0.x; a0.y = 2.f * a0.y - p0.y;
        a0.z = 2.f * a0.z - p0.z; a0.w = 2.f * a0.w - p0.w;
        a1.x = 2.f * a1.x - p1.x; a1.y = 2.f * a1.y - p1.y;
        a1.z = 2.f * a1.z - p1.z; a1.w = 2.f * a1.w - p1.w;
    }
    xn[rb + lane] = a0;
    xn[rb + 64 + lane] = a1;
}

__global__ __launch_bounds__(256) void k_gemm2(const float* __restrict__ xa,
                                               const float* __restrict__ xb,
                                               const float* __restrict__ W,
                                               float* __restrict__ out,
                                               int ka, int kb, int accum) {
    __shared__ __align__(16) float Wa[64 * 64];
    __shared__ __align__(16) float Wb[64 * 64];
    __shared__ __align__(16) float xsa[4 * Cn];
    __shared__ __align__(16) float xsb[4 * Cn];
    int t = threadIdx.x;
    size_t m0 = (size_t)blockIdx.x * 4;
    for (int i = t; i < 4096; i += 256) {
        int f = i >> 6, fo = i & 63;
        Wa[i] = W[(f * Kn + ka) * FOUTn + fo];
        Wb[i] = W[(f * Kn + kb) * FOUTn + fo];
    }
    for (int i = t; i < 4 * Cn; i += 256) {
        xsa[i] = xa[m0 * Cn + i];
        xsb[i] = xb[m0 * Cn + i];
    }
    __syncthreads();
    int fo  = (t & 15) * 4;
    int idx = t >> 4;
    int m   = idx & 3;
    int bq  = idx >> 2;
    float4 acc0 = make_float4(0.f, 0.f, 0.f, 0.f);
    float4 acc1 = make_float4(0.f, 0.f, 0.f, 0.f);
    for (int f = 0; f < 64; ++f) {
        float4 wa = *(const float4*)&Wa[f * 64 + fo];
        float a0 = xsa[m * Cn + bq * 64 + f];
        float a1 = xsa[m * Cn + (bq + 4) * 64 + f];
        acc0.x += a0 * wa.x; acc0.y += a0 * wa.y; acc0.z += a0 * wa.z; acc0.w += a0 * wa.w;
        acc1.x += a1 * wa.x; acc1.y += a1 * wa.y; acc1.z += a1 * wa.z; acc1.w += a1 * wa.w;
        float4 wb = *(const float4*)&Wb[f * 64 + fo];
        float b0 = xsb[m * Cn + bq * 64 + f];
        float b1 = xsb[m * Cn + (bq + 4) * 64 + f];
        acc0.x += b0 * wb.x; acc0.y += b0 * wb.y; acc0.z += b0 * wb.z; acc0.w += b0 * wb.w;
        acc1.x += b1 * wb.x; acc1.y += b1 * wb.y; acc1.z += b1 * wb.z; acc1.w += b1 * wb.w;
    }
    size_t o0 = (((size_t)bq * Mn) + (m0 + m)) * FOUTn + fo;
    size_t o1 = (((size_t)(bq + 4) * Mn) + (m0 + m)) * FOUTn + fo;
    float4* out4_0 = (float4*)&out[o0];
    float4* out4_1 = (float4*)&out[o1];
    if (accum) {
        float4 c0 = *out4_0, c1 = *out4_1;
        acc0.x += c0.x; acc0.y += c0.y; acc0.z += c0.z; acc0.w += c0.w;
        acc1.x += c1.x; acc1.y += c1.y; acc1.z += c1.z; acc1.w += c1.w;
    }
    *out4_0 = acc0;
    *out4_1 = acc1;
}

// ---------------- launch ----------------

extern "C" void kernel_launch(void* const* d_in, const int* in_sizes, int n_in,
                              void* d_out, int out_size, void* d_ws, size_t ws_size,
                              hipStream_t stream) {
    const float* x         = (const float*)d_in[0];
    const float* edge_vals = (const float*)d_in[1];
    const float* W         = (const float*)d_in[2];
    const int*   edge_rows = (const int*)d_in[3];
    const int*   edge_cols = (const int*)d_in[4];
    float* out = (float*)d_out;

    char* ws = (char*)d_ws;
    const size_t bufB = (size_t)Mn * Cn * sizeof(float);   // 81.92 MB fp32 level
    const size_t bufH = (size_t)Mn * Cn * sizeof(ushort);  // 40.96 MB fp16 level
    const size_t wfB  = 12 * 4 * 64 * 8 * sizeof(ushort);  // 48 KB
    const size_t csrB = (size_t)(Mn + 4 + Mn) * 4 + (size_t)NNZn * 8;  // ~2.9 MB

    const int spmm_grid = Mn / 4;      // 10000
    const int gemm_grid = MT * 8;      // 5000, b-major

    // primary plan: 6 fp16 level slots (248.69 MB total), layout [lev][m][c]
    if (ws_size >= 6 * bufH + wfB + csrB) {
        ushort* xh  = (ushort*)ws;                       // slot l at xh + l*Mn*Cn
        ushort* wfr = (ushort*)(ws + 6 * bufH);
        int*    rowptr = (int*)(ws + 6 * bufH + wfB);
        int*    fill   = rowptr + (Mn + 4);              // doubles as wcur
        int2*   csr    = (int2*)(fill + Mn);
        int*    bsum   = (int*)csr;                      // scan scratch in csr buf
        int*    boff   = bsum + 256;
        ushort* slot[6];
        for (int l = 0; l < 6; ++l) slot[l] = xh + (size_t)l * Mn * Cn;

        // CSR build (every call; ws re-poisoned by harness)
        hipMemsetAsync(fill, 0, Mn * sizeof(int), stream);
        k_hist<<<(NNZn + 255) / 256, 256, 0, stream>>>(edge_rows, fill);
        k_scan_part<<<NB, 256, 0, stream>>>(fill, rowptr, bsum);
        k_scan_bsums<<<1, 256, 0, stream>>>(bsum, boff, rowptr);
        k_scan_add<<<NB, 256, 0, stream>>>(rowptr, boff, fill);   // fill := wcur
        k_scatter<<<(NNZn + 255) / 256, 256, 0, stream>>>(edge_rows, edge_cols,
                                                          edge_vals, fill, csr);
        k_wfrag<<<96, 256, 0, stream>>>(W, wfr);

        // transpose into level 0, then the 5 Chebyshev SpMMs
        k_transpose_h<<<Mn / 4, 256, 0, stream>>>(x, slot[0]);
        k_spmm_h<<<spmm_grid, 256, 0, stream>>>(slot[0], slot[0], slot[1],
                                                rowptr, csr, 1);
        k_spmm_h<<<spmm_grid, 256, 0, stream>>>(slot[1], slot[0], slot[2],
                                                rowptr, csr, 0);
        k_spmm_h<<<spmm_grid, 256, 0, stream>>>(slot[2], slot[1], slot[3],
                                                rowptr, csr, 0);
        k_spmm_h<<<spmm_grid, 256, 0, stream>>>(slot[3], slot[2], slot[4],
                                                rowptr, csr, 0);
        k_spmm_h<<<spmm_grid, 256, 0, stream>>>(slot[4], slot[3], slot[5],
                                                rowptr, csr, 0);
        // single-pass projection over all 6 levels (no out RMW)
        k_gemm_mfma<<<gemm_grid, 256, 0, stream>>>(xh, wfr, out);
    } else {
        // fp32 fallback: 3 rotating fp32 buffers + fp32 vector GEMM
        float* buf0 = (float*)(ws);
        float* buf1 = (float*)(ws + bufB);
        float* buf2 = (float*)(ws + 2 * bufB);
        int*   rowptr = (int*)(ws + 3 * bufB);
        int*   fill   = rowptr + (Mn + 4);
        int2*  csr    = (int2*)(fill + Mn);
        int*   bsum   = (int*)csr;
        int*   boff   = bsum + 256;
        hipMemsetAsync(fill, 0, Mn * sizeof(int), stream);
        k_hist<<<(NNZn + 255) / 256, 256, 0, stream>>>(edge_rows, fill);
        k_scan_part<<<NB, 256, 0, stream>>>(fill, rowptr, bsum);
        k_scan_bsums<<<1, 256, 0, stream>>>(bsum, boff, rowptr);
        k_scan_add<<<NB, 256, 0, stream>>>(rowptr, boff, fill);
        k_scatter<<<(NNZn + 255) / 256, 256, 0, stream>>>(edge_rows, edge_cols,
                                                          edge_vals, fill, csr);
        k_transpose_f<<<Mn, 512, 0, stream>>>(x, buf0);
        k_spmm_f32<<<Mn / 4, 256, 0, stream>>>((const float4*)buf0, (const float4*)buf0,
                                               (float4*)buf1, rowptr, csr, 1);
        k_gemm2<<<Mn / 4, 256, 0, stream>>>(buf0, buf1, W, out, 0, 1, 0);
        k_spmm_f32<<<Mn / 4, 256, 0, stream>>>((const float4*)buf1, (const float4*)buf0,
                                               (float4*)buf2, rowptr, csr, 0);
        k_spmm_f32<<<Mn / 4, 256, 0, stream>>>((const float4*)buf2, (const float4*)buf1,
                                               (float4*)buf0, rowptr, csr, 0);
        k_gemm2<<<Mn / 4, 256, 0, stream>>>(buf2, buf0, W, out, 2, 3, 1);
        k_spmm_f32<<<Mn / 4, 256, 0, stream>>>((const float4*)buf0, (const float4*)buf2,
                                               (float4*)buf1, rowptr, csr, 0);
        k_spmm_f32<<<Mn / 4, 256, 0, stream>>>((const float4*)buf1, (const float4*)buf0,
                                               (float4*)buf2, rowptr, csr, 0);
        k_gemm2<<<Mn / 4, 256, 0, stream>>>(buf1, buf2, W, out, 4, 5, 1);
    }
}